// Round 4
// baseline (461.685 us; speedup 1.0000x reference)
//
#include <hip/hip_runtime.h>
#include <hip/hip_bf16.h>
#include <math.h>

#define N 8192
#define FIN 256
#define D 64
#define ALPHA 0.2f

typedef __attribute__((ext_vector_type(8))) short bf16x8;
typedef __attribute__((ext_vector_type(4))) float f32x4;

// ---------------- Kernel 0: pack mask int32 -> 1 bit/elem (8 MB, L2-resident) --
// thread t: ints [8t, 8t+8) -> byte t. Wave reads 2 KB contiguous, writes 64 B.
__global__ __launch_bounds__(256) void k_pack(
    const int* __restrict__ mask, unsigned char* __restrict__ mp)
{
    const size_t t = (size_t)blockIdx.x * 256 + threadIdx.x;
    const int4* s = (const int4*)mask + 2 * t;
    const int4 a = s[0], b = s[1];
    unsigned v = (a.x != 0 ? 1u : 0u) | (a.y != 0 ? 2u : 0u)
               | (a.z != 0 ? 4u : 0u) | (a.w != 0 ? 8u : 0u)
               | (b.x != 0 ? 16u : 0u) | (b.y != 0 ? 32u : 0u)
               | (b.z != 0 ? 64u : 0u) | (b.w != 0 ? 128u : 0u);
    mp[t] = (unsigned char)v;
}

// ---------------- Kernel 1: h = x@trans (fp32), e1/e2 (fp32), hT bf16 transposed
__global__ __launch_bounds__(256) void k_h_e(
    const float* __restrict__ x, const float* __restrict__ trans,
    const float* __restrict__ attn,
    __hip_bfloat16* __restrict__ hT, float* __restrict__ e1, float* __restrict__ e2)
{
    __shared__ float xs[8 * FIN];            // [row][k]
    __shared__ __hip_bfloat16 hl[8 * D];     // [row][d]
    const int t = threadIdx.x;
    const int r0 = blockIdx.x * 8;

    #pragma unroll
    for (int v = 0; v < 2; ++v) {
        int idx = t + 256 * v;
        ((float4*)xs)[idx] = ((const float4*)(x + (size_t)r0 * FIN))[idx];
    }
    __syncthreads();

    const int lane = t & 63, w = t >> 6;
    const float* xa = xs + (2 * w) * FIN;
    const float* xb = xs + (2 * w + 1) * FIN;
    float acca = 0.f, accb = 0.f;
    #pragma unroll 8
    for (int k = 0; k < FIN; ++k) {
        const float tv = trans[k * D + lane];
        acca = fmaf(xa[k], tv, acca);
        accb = fmaf(xb[k], tv, accb);
    }
    const int ra = r0 + 2 * w, rb = ra + 1;

    const float a1 = attn[lane], a2 = attn[D + lane];
    float p1a = acca * a1, p2a = acca * a2;
    float p1b = accb * a1, p2b = accb * a2;
    #pragma unroll
    for (int mm = 1; mm <= 32; mm <<= 1) {
        p1a += __shfl_xor(p1a, mm);
        p2a += __shfl_xor(p2a, mm);
        p1b += __shfl_xor(p1b, mm);
        p2b += __shfl_xor(p2b, mm);
    }
    if (lane == 0) { e1[ra] = p1a; e2[ra] = p2a; e1[rb] = p1b; e2[rb] = p2b; }

    hl[(2 * w) * D + lane]     = __float2bfloat16(acca);
    hl[(2 * w + 1) * D + lane] = __float2bfloat16(accb);
    __syncthreads();
    if (t < D) {
        union { bf16x8 v; __hip_bfloat16 h[8]; } o;
        #pragma unroll
        for (int r = 0; r < 8; ++r) o.h[r] = hl[r * D + t];
        *(bf16x8*)(hT + (size_t)t * N + r0) = o.v;
    }
}

// ---------------- Kernel 2: fused masked softmax-attention via MFMA ------------
// Wave owns 16 rows x all 64 d; A-frag (P) built in-register from 1 mask BYTE
// per lane per iter (bit-packed; 64-B line serves 16 iters -> L1-hit stream).
// Manual 2-stage register pipeline: iter+1 loads issued before iter's compute.
__global__ __launch_bounds__(256) void k_attn(
    const unsigned char* __restrict__ mp, const __hip_bfloat16* __restrict__ hT,
    const float* __restrict__ e1, const float* __restrict__ e2,
    float* __restrict__ acc_part, float* __restrict__ l_part, int cs)
{
    const int t = threadIdx.x;
    const int lane = t & 63, wave = t >> 6;
    const int i0 = (blockIdx.y * 4 + wave) * 16;
    const int sp = blockIdx.x;
    const int c0 = sp * cs;
    const int m = lane & 15, quad = lane >> 4;
    const int row = i0 + m;
    const float er = e1[row];

    // packed-mask byte pointer for (row, cols jb..jb+7); advances 4 B per iter
    const unsigned char* mb = mp + ((size_t)row << 10) + (c0 >> 3) + quad;

    f32x4 acc0 = {0.f, 0.f, 0.f, 0.f};
    f32x4 acc1 = {0.f, 0.f, 0.f, 0.f};
    f32x4 acc2 = {0.f, 0.f, 0.f, 0.f};
    f32x4 acc3 = {0.f, 0.f, 0.f, 0.f};
    float lsum = 0.f;

    const __hip_bfloat16* hb0 = hT + (size_t)(m     ) * N;
    const __hip_bfloat16* hb1 = hT + (size_t)(m + 16) * N;
    const __hip_bfloat16* hb2 = hT + (size_t)(m + 32) * N;
    const __hip_bfloat16* hb3 = hT + (size_t)(m + 48) * N;

    const int jb0 = c0 + quad * 8;
    const int iters = cs >> 5;

    // stage-0 prefetch
    unsigned mc = mb[0];
    float4 ea = *(const float4*)(e2 + jb0);
    float4 eb = *(const float4*)(e2 + jb0 + 4);
    bf16x8 b0 = *(const bf16x8*)(hb0 + jb0);
    bf16x8 b1 = *(const bf16x8*)(hb1 + jb0);
    bf16x8 b2 = *(const bf16x8*)(hb2 + jb0);
    bf16x8 b3 = *(const bf16x8*)(hb3 + jb0);

    for (int it = 0; it < iters; ++it) {
        // prefetch iter+1 (unconditional; last-iter overrun stays inside d_ws)
        const int jn = jb0 + (it + 1) * 32;
        const unsigned mn = mb[(it + 1) * 4];
        const float4 na = *(const float4*)(e2 + jn);
        const float4 nb = *(const float4*)(e2 + jn + 4);
        const bf16x8 n0 = *(const bf16x8*)(hb0 + jn);
        const bf16x8 n1 = *(const bf16x8*)(hb1 + jn);
        const bf16x8 n2 = *(const bf16x8*)(hb2 + jn);
        const bf16x8 n3 = *(const bf16x8*)(hb3 + jn);

        float s0 = er + ea.x; s0 = s0 > 0.f ? s0 : ALPHA * s0;
        float s1 = er + ea.y; s1 = s1 > 0.f ? s1 : ALPHA * s1;
        float s2 = er + ea.z; s2 = s2 > 0.f ? s2 : ALPHA * s2;
        float s3 = er + ea.w; s3 = s3 > 0.f ? s3 : ALPHA * s3;
        float s4 = er + eb.x; s4 = s4 > 0.f ? s4 : ALPHA * s4;
        float s5 = er + eb.y; s5 = s5 > 0.f ? s5 : ALPHA * s5;
        float s6 = er + eb.z; s6 = s6 > 0.f ? s6 : ALPHA * s6;
        float s7 = er + eb.w; s7 = s7 > 0.f ? s7 : ALPHA * s7;
        const float p0 = (mc & 1u)   ? __expf(s0) : 0.f;
        const float p1 = (mc & 2u)   ? __expf(s1) : 0.f;
        const float p2 = (mc & 4u)   ? __expf(s2) : 0.f;
        const float p3 = (mc & 8u)   ? __expf(s3) : 0.f;
        const float p4 = (mc & 16u)  ? __expf(s4) : 0.f;
        const float p5 = (mc & 32u)  ? __expf(s5) : 0.f;
        const float p6 = (mc & 64u)  ? __expf(s6) : 0.f;
        const float p7 = (mc & 128u) ? __expf(s7) : 0.f;

        union { bf16x8 v; __hip_bfloat162 h2[4]; } af;
        af.h2[0] = __float22bfloat162_rn(make_float2(p0, p1));
        af.h2[1] = __float22bfloat162_rn(make_float2(p2, p3));
        af.h2[2] = __float22bfloat162_rn(make_float2(p4, p5));
        af.h2[3] = __float22bfloat162_rn(make_float2(p6, p7));

        lsum += ((p0 + p1) + (p2 + p3)) + ((p4 + p5) + (p6 + p7));

        acc0 = __builtin_amdgcn_mfma_f32_16x16x32_bf16(af.v, b0, acc0, 0, 0, 0);
        acc1 = __builtin_amdgcn_mfma_f32_16x16x32_bf16(af.v, b1, acc1, 0, 0, 0);
        acc2 = __builtin_amdgcn_mfma_f32_16x16x32_bf16(af.v, b2, acc2, 0, 0, 0);
        acc3 = __builtin_amdgcn_mfma_f32_16x16x32_bf16(af.v, b3, acc3, 0, 0, 0);

        mc = mn; ea = na; eb = nb; b0 = n0; b1 = n1; b2 = n2; b3 = n3;
    }

    // row m's columns live in lanes m, m+16, m+32, m+48
    lsum += __shfl_xor(lsum, 16);
    lsum += __shfl_xor(lsum, 32);
    if (quad == 0) l_part[(size_t)sp * N + row] = lsum;

    // C/D layout: col = lane&15 (+16 per acc frag), row = quad*4 + reg
    #pragma unroll
    for (int reg = 0; reg < 4; ++reg) {
        const size_t rbase = ((size_t)sp * N + i0 + quad * 4 + reg) * D;
        acc_part[rbase + m     ] = acc0[reg];
        acc_part[rbase + m + 16] = acc1[reg];
        acc_part[rbase + m + 32] = acc2[reg];
        acc_part[rbase + m + 48] = acc3[reg];
    }
}

// ---------------- Kernel 3: combine splits, divide by l ------------------------
__global__ __launch_bounds__(256) void k_reduce(
    const float* __restrict__ acc_part, const float* __restrict__ l_part,
    float* __restrict__ out, int nsplit)
{
    const int idx = blockIdx.x * 256 + threadIdx.x;
    const int row = idx >> 6;
    float sum = 0.f, l = 0.f;
    for (int s = 0; s < nsplit; ++s) {
        sum += acc_part[(size_t)s * N * D + idx];
        l   += l_part[(size_t)s * N + row];
    }
    out[idx] = sum / l;
}

extern "C" void kernel_launch(void* const* d_in, const int* in_sizes, int n_in,
                              void* d_out, int out_size, void* d_ws, size_t ws_size,
                              hipStream_t stream) {
    const float* x     = (const float*)d_in[0];
    const int*   mask  = (const int*)d_in[1];
    const float* trans = (const float*)d_in[2];
    const float* attn  = (const float*)d_in[3];
    float* out = (float*)d_out;

    char* ws = (char*)d_ws;
    __hip_bfloat16* hT = (__hip_bfloat16*)ws;                 // 1 MB
    char* p = ws + (size_t)D * N * sizeof(__hip_bfloat16);
    float* e1 = (float*)p;            p += (size_t)N * sizeof(float);
    float* e2 = (float*)p;            p += (size_t)N * sizeof(float);
    unsigned char* mp = (unsigned char*)p;  p += (size_t)N * (N / 8);  // 8 MB
    // choose nsplit
    const size_t used = (size_t)(p - ws);
    int nsplit = 1;
    const int cands[4] = {8, 4, 2, 1};
    for (int ci = 0; ci < 4; ++ci) {
        int s = cands[ci];
        size_t need = used + (size_t)s * N * sizeof(float)
                    + (size_t)s * N * D * sizeof(float) + 4096;
        if (need <= ws_size) { nsplit = s; break; }
    }
    float* l_part = (float*)p;
    float* acc_part = l_part + (size_t)nsplit * N;

    k_pack<<<(N / 16) * (N / 128), 256, 0, stream>>>(mask, mp);   // 32768 blocks
    k_h_e<<<N / 8, 256, 0, stream>>>(x, trans, attn, hT, e1, e2);
    dim3 g2(nsplit, N / 64);
    k_attn<<<g2, 256, 0, stream>>>(mp, hT, e1, e2, acc_part, l_part, N / nsplit);
    k_reduce<<<(N * D) / 256, 256, 0, stream>>>(acc_part, l_part, out, nsplit);
}

// Round 6
// 427.660 us; speedup vs baseline: 1.0796x; 1.0796x over previous
//
#include <hip/hip_runtime.h>
#include <hip/hip_bf16.h>
#include <math.h>

#define N 8192
#define FIN 256
#define D 64
#define ALPHA 0.2f

typedef __attribute__((ext_vector_type(8))) short bf16x8;
typedef __attribute__((ext_vector_type(4))) float f32x4;

// ---------------- Kernel 0: mask -> fragment-ordered bitmask mF ---------------
// mF[(rt*256 + cb)*64 + jgrp*16 + m] = bits of mask[rt*16+m][cb*32+jgrp*8 .. +8]
// Reads coalesced (16 thr x 32 B per row); writes 8 MB scattered bytes (cheap).
__global__ __launch_bounds__(256) void k_pack(
    const int* __restrict__ mask, unsigned char* __restrict__ mF)
{
    const int t = threadIdx.x;
    const int rt = blockIdx.x >> 1;
    const int half = blockIdx.x & 1;
    const int row = rt * 16 + (t >> 4);
    const int c = t & 15;
    const int m = t >> 4;
    for (int cc = half * (N / 2); cc < (half + 1) * (N / 2); cc += 128) {
        const int col = cc + c * 8;
        const int4 a = *(const int4*)(mask + (size_t)row * N + col);
        const int4 b = *(const int4*)(mask + (size_t)row * N + col + 4);
        unsigned v = (a.x != 0 ? 1u : 0u) | (a.y != 0 ? 2u : 0u)
                   | (a.z != 0 ? 4u : 0u) | (a.w != 0 ? 8u : 0u)
                   | (b.x != 0 ? 16u : 0u) | (b.y != 0 ? 32u : 0u)
                   | (b.z != 0 ? 64u : 0u) | (b.w != 0 ? 128u : 0u);
        const int cb = col >> 5;
        const int jgrp = c & 3;
        mF[((size_t)rt * 256 + cb) * 64 + jgrp * 16 + m] = (unsigned char)v;
    }
}

// ---------------- Kernel 1: h = x@trans (fp32), e1/e2 (fp32), hF fragment-order
// 1024 blocks x 8 rows. hF[((cb*4+q)*64 + jgrp*16 + m)*8 + r] = h[r0+r][q*16+m]
// where cb = r0>>5, jgrp = (r0>>3)&3  (j-dim of the MFMA B fragment = h's row).
__global__ __launch_bounds__(256) void k_h_e(
    const float* __restrict__ x, const float* __restrict__ trans,
    const float* __restrict__ attn,
    __hip_bfloat16* __restrict__ hF, float* __restrict__ e1, float* __restrict__ e2)
{
    __shared__ float xs[8 * FIN];            // [row][k]
    __shared__ __hip_bfloat16 hl[8 * D];     // [row][d]
    const int t = threadIdx.x;
    const int r0 = blockIdx.x * 8;

    #pragma unroll
    for (int v = 0; v < 2; ++v) {
        int idx = t + 256 * v;
        ((float4*)xs)[idx] = ((const float4*)(x + (size_t)r0 * FIN))[idx];
    }
    __syncthreads();

    const int lane = t & 63, w = t >> 6;
    const float* xa = xs + (2 * w) * FIN;
    const float* xb = xs + (2 * w + 1) * FIN;
    float acca = 0.f, accb = 0.f;
    #pragma unroll 8
    for (int k = 0; k < FIN; ++k) {
        const float tv = trans[k * D + lane];
        acca = fmaf(xa[k], tv, acca);
        accb = fmaf(xb[k], tv, accb);
    }
    const int ra = r0 + 2 * w, rb = ra + 1;

    const float a1 = attn[lane], a2 = attn[D + lane];
    float p1a = acca * a1, p2a = acca * a2;
    float p1b = accb * a1, p2b = accb * a2;
    #pragma unroll
    for (int mm = 1; mm <= 32; mm <<= 1) {
        p1a += __shfl_xor(p1a, mm);
        p2a += __shfl_xor(p2a, mm);
        p1b += __shfl_xor(p1b, mm);
        p2b += __shfl_xor(p2b, mm);
    }
    if (lane == 0) { e1[ra] = p1a; e2[ra] = p2a; e1[rb] = p1b; e2[rb] = p2b; }

    hl[(2 * w) * D + lane]     = __float2bfloat16(acca);
    hl[(2 * w + 1) * D + lane] = __float2bfloat16(accb);
    __syncthreads();
    if (t < D) {
        const int q = t >> 4, m = t & 15;
        const int cb = r0 >> 5, jgrp = (r0 >> 3) & 3;
        union { bf16x8 v; __hip_bfloat16 h[8]; } o;
        #pragma unroll
        for (int r = 0; r < 8; ++r) o.h[r] = hl[r * D + q * 16 + m];
        *(bf16x8*)(hF + (((size_t)cb * 4 + q) * 64 + jgrp * 16 + m) * 8) = o.v;
    }
}

// ---------------- Kernel 2: fused masked softmax-attention via MFMA ------------
// All global loads lane-contiguous: 1 byte/lane bitmask (64 B burst) + 4 x 16B/lane
// hF fragments (1 KB bursts) + e2 broadcast. VALU body identical to R3.
__global__ __launch_bounds__(256) void k_attn(
    const unsigned char* __restrict__ mF, const __hip_bfloat16* __restrict__ hF,
    const float* __restrict__ e1, const float* __restrict__ e2,
    float* __restrict__ acc_part, float* __restrict__ l_part, int cs)
{
    const int t = threadIdx.x;
    const int lane = t & 63, wave = t >> 6;
    const int i0 = (blockIdx.y * 4 + wave) * 16;
    const int rt = blockIdx.y * 4 + wave;
    const int sp = blockIdx.x;
    const int c0 = sp * cs;
    const int m = lane & 15, quad = lane >> 4;
    const int row = i0 + m;
    const float er = e1[row];

    const unsigned char* mbp = mF + ((size_t)rt * 256 + (c0 >> 5)) * 64 + lane;
    const __hip_bfloat16* hfp = hF + (((size_t)(c0 >> 5)) * 4 * 64 + lane) * 8;

    f32x4 acc0 = {0.f, 0.f, 0.f, 0.f};
    f32x4 acc1 = {0.f, 0.f, 0.f, 0.f};
    f32x4 acc2 = {0.f, 0.f, 0.f, 0.f};
    f32x4 acc3 = {0.f, 0.f, 0.f, 0.f};
    float lsum = 0.f;

    const int iters = cs >> 5;
    for (int it = 0; it < iters; ++it) {
        const int jb = c0 + it * 32 + quad * 8;
        const unsigned mc = mbp[it * 64];
        const float4 ea = *(const float4*)(e2 + jb);
        const float4 eb = *(const float4*)(e2 + jb + 4);
        const bf16x8* hq = (const bf16x8*)(hfp + (size_t)it * 2048);
        const bf16x8 b0 = hq[0];       // +q*512 elements = +64 bf16x8
        const bf16x8 b1 = hq[64];
        const bf16x8 b2 = hq[128];
        const bf16x8 b3 = hq[192];

        float s0 = er + ea.x; s0 = s0 > 0.f ? s0 : ALPHA * s0;
        float s1 = er + ea.y; s1 = s1 > 0.f ? s1 : ALPHA * s1;
        float s2 = er + ea.z; s2 = s2 > 0.f ? s2 : ALPHA * s2;
        float s3 = er + ea.w; s3 = s3 > 0.f ? s3 : ALPHA * s3;
        float s4 = er + eb.x; s4 = s4 > 0.f ? s4 : ALPHA * s4;
        float s5 = er + eb.y; s5 = s5 > 0.f ? s5 : ALPHA * s5;
        float s6 = er + eb.z; s6 = s6 > 0.f ? s6 : ALPHA * s6;
        float s7 = er + eb.w; s7 = s7 > 0.f ? s7 : ALPHA * s7;
        const float p0 = (mc & 1u)   ? __expf(s0) : 0.f;
        const float p1 = (mc & 2u)   ? __expf(s1) : 0.f;
        const float p2 = (mc & 4u)   ? __expf(s2) : 0.f;
        const float p3 = (mc & 8u)   ? __expf(s3) : 0.f;
        const float p4 = (mc & 16u)  ? __expf(s4) : 0.f;
        const float p5 = (mc & 32u)  ? __expf(s5) : 0.f;
        const float p6 = (mc & 64u)  ? __expf(s6) : 0.f;
        const float p7 = (mc & 128u) ? __expf(s7) : 0.f;

        union { bf16x8 v; __hip_bfloat162 h2[4]; } af;
        af.h2[0] = __float22bfloat162_rn(make_float2(p0, p1));
        af.h2[1] = __float22bfloat162_rn(make_float2(p2, p3));
        af.h2[2] = __float22bfloat162_rn(make_float2(p4, p5));
        af.h2[3] = __float22bfloat162_rn(make_float2(p6, p7));

        lsum += ((p0 + p1) + (p2 + p3)) + ((p4 + p5) + (p6 + p7));

        acc0 = __builtin_amdgcn_mfma_f32_16x16x32_bf16(af.v, b0, acc0, 0, 0, 0);
        acc1 = __builtin_amdgcn_mfma_f32_16x16x32_bf16(af.v, b1, acc1, 0, 0, 0);
        acc2 = __builtin_amdgcn_mfma_f32_16x16x32_bf16(af.v, b2, acc2, 0, 0, 0);
        acc3 = __builtin_amdgcn_mfma_f32_16x16x32_bf16(af.v, b3, acc3, 0, 0, 0);
    }

    // row m's columns live in lanes m, m+16, m+32, m+48
    lsum += __shfl_xor(lsum, 16);
    lsum += __shfl_xor(lsum, 32);
    if (quad == 0) l_part[(size_t)sp * N + row] = lsum;

    // C/D layout: col = lane&15 (+16 per acc frag), row = quad*4 + reg
    #pragma unroll
    for (int reg = 0; reg < 4; ++reg) {
        const size_t rbase = ((size_t)sp * N + i0 + quad * 4 + reg) * D;
        acc_part[rbase + m     ] = acc0[reg];
        acc_part[rbase + m + 16] = acc1[reg];
        acc_part[rbase + m + 32] = acc2[reg];
        acc_part[rbase + m + 48] = acc3[reg];
    }
}

// ---------------- Kernel 3: combine splits, divide by l ------------------------
__global__ __launch_bounds__(256) void k_reduce(
    const float* __restrict__ acc_part, const float* __restrict__ l_part,
    float* __restrict__ out, int nsplit)
{
    const int idx = blockIdx.x * 256 + threadIdx.x;
    const int row = idx >> 6;
    float sum = 0.f, l = 0.f;
    for (int s = 0; s < nsplit; ++s) {
        sum += acc_part[(size_t)s * N * D + idx];
        l   += l_part[(size_t)s * N + row];
    }
    out[idx] = sum / l;
}

extern "C" void kernel_launch(void* const* d_in, const int* in_sizes, int n_in,
                              void* d_out, int out_size, void* d_ws, size_t ws_size,
                              hipStream_t stream) {
    const float* x     = (const float*)d_in[0];
    const int*   mask  = (const int*)d_in[1];
    const float* trans = (const float*)d_in[2];
    const float* attn  = (const float*)d_in[3];
    float* out = (float*)d_out;

    char* ws = (char*)d_ws;
    __hip_bfloat16* hF = (__hip_bfloat16*)ws;                 // 1 MB
    char* p = ws + (size_t)D * N * sizeof(__hip_bfloat16);
    float* e1 = (float*)p;            p += (size_t)N * sizeof(float);
    float* e2 = (float*)p;            p += (size_t)N * sizeof(float);
    unsigned char* mF = (unsigned char*)p;  p += (size_t)N * (N / 8);  // 8 MB

    const size_t used = (size_t)(p - ws);
    int nsplit = 8;
    while (nsplit > 1) {
        size_t need = used + (size_t)nsplit * N * sizeof(float)
                    + (size_t)nsplit * N * D * sizeof(float);
        if (need <= ws_size) break;
        nsplit >>= 1;
    }
    float* l_part = (float*)p;
    float* acc_part = l_part + (size_t)nsplit * N;

    k_pack<<<(N / 16) * 2, 256, 0, stream>>>(mask, mF);     // 1024 blocks
    k_h_e<<<N / 8, 256, 0, stream>>>(x, trans, attn, hF, e1, e2);
    dim3 g2(nsplit, N / 64);
    k_attn<<<g2, 256, 0, stream>>>(mF, hF, e1, e2, acc_part, l_part, N / nsplit);
    k_reduce<<<(N * D) / 256, 256, 0, stream>>>(acc_part, l_part, out, nsplit);
}